// Round 7
// baseline (336.484 us; speedup 1.0000x reference)
//
#include <hip/hip_runtime.h>
#include <hip/hip_cooperative_groups.h>
#include <cstdint>
#include <cstddef>

#define NH 8
#define DH 64
#define DM 512
#define CTX 64
#define BB 2
#define QL 2048
#define TT (QL + CTX - 1)   // 2111
#define HDIM 512
#define KVN 1024
#define KD 512

typedef unsigned short u16;
typedef __attribute__((ext_vector_type(8))) short bf16x8;
typedef __attribute__((ext_vector_type(4))) float f32x4;

__device__ __forceinline__ u16 f2bf(float f) {      // RNE float->bf16
    uint32_t u = __float_as_uint(f);
    u += 0x7FFF + ((u >> 16) & 1);
    return (u16)(u >> 16);
}

#define GLLDS(g, l) __builtin_amdgcn_global_load_lds( \
    (const __attribute__((address_space(1))) void*)(g), \
    (__attribute__((address_space(3))) void*)(l), 16, 0, 0)

struct Ptrs {
    const float *x, *r, *Wkv, *Wq, *bq, *Wr, *Wo;
    float* outp;
    u16 *xb, *rb, *WkvqT, *WrT, *WoT, *kvb, *hqb, *hrb, *attnb;
    float* maskv;
};

// ---------------------------------------------------------------------------
// GEMM unit: 128(M) x 64(N) tile, BK=32, K=512, 256 threads.
// mode 1: G1 split epilogue (kv bf16 / hq+bq bf16 remapped)
// mode 2: G3 row-major bf16, rows < 64
// mode 3: G2 fp32 C
// ---------------------------------------------------------------------------
__device__ __forceinline__ void gemm_unit(
    const u16* __restrict__ A, const u16* __restrict__ BT,
    int m0, int n0, char* smem, int tid, int mode, const Ptrs& p)
{
    u16* As = (u16*)smem;            // 128*32
    u16* Bs = (u16*)(smem + 8192);   // 64*32
    const int lane = tid & 63;
    const int w    = tid >> 6;
    const int wm   = (w >> 1) * 64;
    const int wn   = (w & 1) * 32;

    const u16* ga0 = A  + (size_t)(m0 + (tid >> 2)) * KD + (tid & 3) * 8;
    const u16* ga1 = ga0 + (size_t)64 * KD;
    const u16* gb0 = BT + (size_t)(n0 + (tid >> 2)) * KD + (tid & 3) * 8;

    f32x4 acc[4][2];
#pragma unroll
    for (int i = 0; i < 4; i++)
#pragma unroll
        for (int j = 0; j < 2; j++)
            acc[i][j] = (f32x4){0.f, 0.f, 0.f, 0.f};

    const int fm = lane & 15;
    const int fk = (lane >> 4) * 8;

    for (int kt = 0; kt < KD; kt += 32) {
        __syncthreads();   // protect previous LDS consumers
        GLLDS(ga0 + kt, As + w * 512);
        GLLDS(ga1 + kt, As + 2048 + w * 512);
        GLLDS(gb0 + kt, Bs + w * 512);
        __syncthreads();   // tiles ready

        bf16x8 af[4], bfr[2];
#pragma unroll
        for (int i = 0; i < 4; i++)
            af[i] = *(const bf16x8*)&As[(wm + i * 16 + fm) * 32 + fk];
#pragma unroll
        for (int j = 0; j < 2; j++)
            bfr[j] = *(const bf16x8*)&Bs[(wn + j * 16 + fm) * 32 + fk];
#pragma unroll
        for (int i = 0; i < 4; i++)
#pragma unroll
            for (int j = 0; j < 2; j++)
                acc[i][j] = __builtin_amdgcn_mfma_f32_16x16x32_bf16(af[i], bfr[j], acc[i][j], 0, 0, 0);
    }

    const int fc = lane & 15;
    const int fr = (lane >> 4) * 4;
    if (mode == 1) {
        const bool iskv = (n0 < 1024);
#pragma unroll
        for (int i = 0; i < 4; i++)
#pragma unroll
            for (int rr = 0; rr < 4; rr++) {
                int row = m0 + wm + i * 16 + fr + rr;
                if (row < BB * TT) {
                    if (iskv) {
#pragma unroll
                        for (int j = 0; j < 2; j++) {
                            int col = n0 + wn + j * 16 + fc;
                            p.kvb[(size_t)row * KVN + col] = f2bf(acc[i][j][rr]);
                        }
                    } else {
                        int bb = row / TT;
                        int t  = row - bb * TT;
                        if (t >= CTX - 1) {
                            size_t orow = (size_t)(bb * QL + t - (CTX - 1));
#pragma unroll
                            for (int j = 0; j < 2; j++) {
                                int col = n0 + wn + j * 16 + fc - 1024;
                                p.hqb[orow * HDIM + col] = f2bf(acc[i][j][rr] + p.bq[col]);
                            }
                        }
                    }
                }
            }
    } else if (mode == 2) {
#pragma unroll
        for (int i = 0; i < 4; i++)
#pragma unroll
            for (int rr = 0; rr < 4; rr++) {
                int row = m0 + wm + i * 16 + fr + rr;
                if (row < CTX) {
#pragma unroll
                    for (int j = 0; j < 2; j++) {
                        int col = n0 + wn + j * 16 + fc;
                        p.hrb[(size_t)row * HDIM + col] = f2bf(acc[i][j][rr]);
                    }
                }
            }
    } else {
#pragma unroll
        for (int i = 0; i < 4; i++)
#pragma unroll
            for (int rr = 0; rr < 4; rr++) {
                int row = m0 + wm + i * 16 + fr + rr;
#pragma unroll
                for (int j = 0; j < 2; j++) {
                    int col = n0 + wn + j * 16 + fc;
                    p.outp[(size_t)row * DM + col] = acc[i][j][rr];
                }
            }
    }
}

// ---------------------------------------------------------------------------
// Stage A unit: casts, weight transposes, pad mask. u in [0, 2589).
// ---------------------------------------------------------------------------
__device__ __forceinline__ void stageA(int u, int tid, char* smem, const Ptrs& p)
{
    int bid = u;
    if (bid < 2111) {                            // x cast
        int i = bid * 256 + tid;
        float4 v = ((const float4*)p.x)[i];
        ushort4 o; o.x = f2bf(v.x); o.y = f2bf(v.y); o.z = f2bf(v.z); o.w = f2bf(v.w);
        ((ushort4*)p.xb)[i] = o;
        return;
    }
    bid -= 2111;
    if (bid < 32) {                              // r cast
        int i = bid * 256 + tid;
        float4 v = ((const float4*)p.r)[i];
        ushort4 o; o.x = f2bf(v.x); o.y = f2bf(v.y); o.z = f2bf(v.z); o.w = f2bf(v.w);
        ((ushort4*)p.rb)[i] = o;
        return;
    }
    bid -= 32;
    if (bid >= 320) {                            // pad mask (126 units)
        int* anyflag = (int*)(smem + 16896);
        int idx = bid - 320;
        int t = idx >> 1, b = idx & 1;
        const float* row = p.x + (size_t)(b * TT + t) * DM;
        bool nz = (row[tid] != 0.f) || (row[tid + 256] != 0.f);
        if (tid == 0) *anyflag = 0;
        __syncthreads();
        unsigned long long bal = __ballot(nz);
        if ((tid & 63) == 0 && bal) atomicOr(anyflag, 1);
        __syncthreads();
        if (tid == 0) p.maskv[b * 64 + t] = *anyflag ? 0.f : -1e30f;
        return;
    }
    // weight transposes (320 units)
    float (*tile)[65] = (float(*)[65])smem;
    const float* W; u16* WT; int N; int tidx;
    if (bid < 128)      { W = p.Wkv; WT = p.WkvqT;                      N = 1024; tidx = bid; }
    else if (bid < 192) { W = p.Wq;  WT = p.WkvqT + (size_t)1024 * 512; N = 512;  tidx = bid - 128; }
    else if (bid < 256) { W = p.Wr;  WT = p.WrT;                        N = 512;  tidx = bid - 192; }
    else                { W = p.Wo;  WT = p.WoT;                        N = 512;  tidx = bid - 256; }
    const int tpr = N / 64;
    const int kb = (tidx / tpr) * 64, nbo = (tidx % tpr) * 64;
    const int c4 = (tid & 15) * 4;
    __syncthreads();   // protect tile reuse across loop iterations
    for (int kk = tid >> 4; kk < 64; kk += 16) {
        float4 v = *(const float4*)&W[(size_t)(kb + kk) * N + nbo + c4];
        tile[kk][c4 + 0] = v.x; tile[kk][c4 + 1] = v.y;
        tile[kk][c4 + 2] = v.z; tile[kk][c4 + 3] = v.w;
    }
    __syncthreads();
    for (int nn = tid >> 4; nn < 64; nn += 16) {
        ushort4 o;
        o.x = f2bf(tile[c4 + 0][nn]); o.y = f2bf(tile[c4 + 1][nn]);
        o.z = f2bf(tile[c4 + 2][nn]); o.w = f2bf(tile[c4 + 3][nn]);
        *(ushort4*)&WT[(size_t)(nbo + nn) * KD + kb + c4] = o;
    }
}

// ---------------------------------------------------------------------------
// Stage B unit: G1 (792) + G3 (8). u in [0, 800).
// ---------------------------------------------------------------------------
__device__ __forceinline__ void stageB(int u, int tid, char* smem, const Ptrs& p)
{
    if (u < 792) {
        int mu = u / 24, nu = u - mu * 24;
        gemm_unit(p.xb, p.WkvqT, mu * 128, nu * 64, smem, tid, 1, p);
    } else {
        gemm_unit(p.rb, p.WrT, 0, (u - 792) * 64, smem, tid, 2, p);
    }
}

// ---------------------------------------------------------------------------
// Stage C unit: MFMA attention. u in [0, 512).
// ---------------------------------------------------------------------------
__device__ __forceinline__ void stageC(int u, int tid, char* smem, const Ptrs& p)
{
    float* sprime = (float*)smem;                 // [4][16][80]
    u16*   vTs    = (u16*)smem;                   // [64][136] (aliases sprime)
    float* s2s    = (float*)(smem + 20480);       // [4][16][68]
    u16*   wband  = (u16*)(smem + 37888);         // [64][136]

    const int q0 = (u & 31) * 64;
    const int h  = (u >> 5) & 7;
    const int b  = u >> 8;
    const int lane = tid & 63;
    const int w    = tid >> 6;
    const int qb   = q0 + w * 16;

    __syncthreads();   // protect smem reuse entering attn
    {
        uint32_t* wz = (uint32_t*)wband;
#pragma unroll
        for (int i = 0; i < 17; i++) wz[tid + i * 256] = 0;
    }
    __syncthreads();

    const int fm = lane & 15;
    const int fk = (lane >> 4) * 8;

    const u16* hqrow = p.hqb + (size_t)(b * QL + qb + fm) * HDIM + h * DH + fk;
    bf16x8 afr0 = *(const bf16x8*)(hqrow);
    bf16x8 afr1 = *(const bf16x8*)(hqrow + 32);

    // QK': S'[16 x 80]
    {
        const u16* kbase = p.kvb + (size_t)(b * TT + qb + fm) * KVN + h * DH + fk;
#pragma unroll
        for (int nt = 0; nt < 5; nt++) {
            bf16x8 b0 = *(const bf16x8*)(kbase + (size_t)nt * 16 * KVN);
            bf16x8 b1 = *(const bf16x8*)(kbase + (size_t)nt * 16 * KVN + 32);
            f32x4 acc = (f32x4){0.f, 0.f, 0.f, 0.f};
            acc = __builtin_amdgcn_mfma_f32_16x16x32_bf16(afr0, b0, acc, 0, 0, 0);
            acc = __builtin_amdgcn_mfma_f32_16x16x32_bf16(afr1, b1, acc, 0, 0, 0);
            const int row = (lane >> 4) * 4;
#pragma unroll
            for (int rr = 0; rr < 4; rr++)
                sprime[w * 1280 + (row + rr) * 80 + nt * 16 + fm] = acc[rr];
        }
    }
    // S2[16 x 64] = hq @ hr^T
    {
        const u16* hrbase = p.hrb + (size_t)fm * HDIM + h * DH + fk;
#pragma unroll
        for (int nc = 0; nc < 4; nc++) {
            bf16x8 b0 = *(const bf16x8*)(hrbase + (size_t)nc * 16 * HDIM);
            bf16x8 b1 = *(const bf16x8*)(hrbase + (size_t)nc * 16 * HDIM + 32);
            f32x4 acc = (f32x4){0.f, 0.f, 0.f, 0.f};
            acc = __builtin_amdgcn_mfma_f32_16x16x32_bf16(afr0, b0, acc, 0, 0, 0);
            acc = __builtin_amdgcn_mfma_f32_16x16x32_bf16(afr1, b1, acc, 0, 0, 0);
            const int row = (lane >> 4) * 4;
#pragma unroll
            for (int rr = 0; rr < 4; rr++)
                s2s[w * 1088 + (row + rr) * 68 + nc * 16 + fm] = acc[rr];
        }
    }

    // softmax
#pragma unroll 1
    for (int i = 0; i < 16; i++) {
        const int qloc = w * 16 + i;
        float s = (sprime[w * 1280 + i * 80 + i + lane] +
                   s2s[w * 1088 + i * 68 + lane]) * 0.125f;
        if (q0 == 0) {
            int t = qloc + lane;
            if (t < 63) s += p.maskv[b * 64 + t];
        }
        float mx = s;
#pragma unroll
        for (int off = 32; off; off >>= 1) mx = fmaxf(mx, __shfl_xor(mx, off, 64));
        float e = __expf(s - mx);
        float sum = e;
#pragma unroll
        for (int off = 32; off; off >>= 1) sum += __shfl_xor(sum, off, 64);
        wband[qloc * 136 + qloc + lane] = f2bf(e / sum);
    }
    __syncthreads();

    // stage vT[d][t]
    {
        const int r0 = tid >> 4;
        const int c4 = (tid & 15) * 4;
        for (int rr = r0; rr < 127; rr += 16) {
            ushort4 vv = *(const ushort4*)&p.kvb[(size_t)(b * TT + q0 + rr) * KVN + HDIM + h * DH + c4];
            vTs[(c4 + 0) * 136 + rr] = vv.x;
            vTs[(c4 + 1) * 136 + rr] = vv.y;
            vTs[(c4 + 2) * 136 + rr] = vv.z;
            vTs[(c4 + 3) * 136 + rr] = vv.w;
        }
        if (tid < 64) vTs[tid * 136 + 127] = 0;
    }
    __syncthreads();

    // PV
    f32x4 oacc[4];
#pragma unroll
    for (int j = 0; j < 4; j++) oacc[j] = (f32x4){0.f, 0.f, 0.f, 0.f};
#pragma unroll
    for (int ks = 0; ks < 4; ks++) {
        bf16x8 wa = *(const bf16x8*)&wband[(w * 16 + fm) * 136 + ks * 32 + fk];
#pragma unroll
        for (int j = 0; j < 4; j++) {
            bf16x8 vb = *(const bf16x8*)&vTs[(j * 16 + fm) * 136 + ks * 32 + fk];
            oacc[j] = __builtin_amdgcn_mfma_f32_16x16x32_bf16(wa, vb, oacc[j], 0, 0, 0);
        }
    }
    {
        const int row = (lane >> 4) * 4;
#pragma unroll
        for (int j = 0; j < 4; j++)
#pragma unroll
            for (int rr = 0; rr < 4; rr++)
                p.attnb[(size_t)(b * QL + qb + row + rr) * HDIM + h * DH + j * 16 + fm] =
                    f2bf(oacc[j][rr]);
    }
}

__device__ __forceinline__ void stageD(int u, int tid, char* smem, const Ptrs& p)
{
    gemm_unit(p.attnb, p.WoT, (u >> 3) * 128, (u & 7) * 64, smem, tid, 3, p);
}

// ---------------------------------------------------------------------------
// Cooperative single-launch pipeline (grid-stride, any legal grid size).
// ---------------------------------------------------------------------------
__global__ __launch_bounds__(256, 2) void fused_all(Ptrs p)
{
    __shared__ __align__(16) char smem[55296];
    cooperative_groups::grid_group gg = cooperative_groups::this_grid();
    const int tid = threadIdx.x;
    const int nb  = gridDim.x;

    for (int u = blockIdx.x; u < 2589; u += nb) stageA(u, tid, smem, p);
    __threadfence(); gg.sync();
    for (int u = blockIdx.x; u < 800; u += nb)  stageB(u, tid, smem, p);
    __threadfence(); gg.sync();
    for (int u = blockIdx.x; u < 512; u += nb)  stageC(u, tid, smem, p);
    __threadfence(); gg.sync();
    for (int u = blockIdx.x; u < 256; u += nb)  stageD(u, tid, smem, p);
}

// ---------------------------------------------------------------------------
// Fallback: same stages as 4 plain launches.
// ---------------------------------------------------------------------------
__global__ __launch_bounds__(256) void k_prep(Ptrs p)
{
    __shared__ __align__(16) char smem[16912];
    stageA(blockIdx.x, threadIdx.x, smem, p);
}
__global__ __launch_bounds__(256) void k_gB(Ptrs p)
{
    __shared__ __align__(16) char smem[12288];
    stageB(blockIdx.x, threadIdx.x, smem, p);
}
__global__ __launch_bounds__(256, 2) void k_attn(Ptrs p)
{
    __shared__ __align__(16) char smem[55296];
    stageC(blockIdx.x, threadIdx.x, smem, p);
}
__global__ __launch_bounds__(256) void k_gD(Ptrs p)
{
    __shared__ __align__(16) char smem[12288];
    stageD(blockIdx.x, threadIdx.x, smem, p);
}

// ---------------------------------------------------------------------------
extern "C" void kernel_launch(void* const* d_in, const int* in_sizes, int n_in,
                              void* d_out, int out_size, void* d_ws, size_t ws_size,
                              hipStream_t stream)
{
    Ptrs p;
    p.x   = (const float*)d_in[0];
    p.r   = (const float*)d_in[1];
    p.Wkv = (const float*)d_in[2];
    p.Wq  = (const float*)d_in[3];
    p.bq  = (const float*)d_in[4];
    p.Wr  = (const float*)d_in[5];
    p.Wo  = (const float*)d_in[6];
    p.outp = (float*)d_out;

    char* w = (char*)d_ws;
    p.xb    = (u16*)w;  w += (size_t)4224 * 512 * 2;
    p.rb    = (u16*)w;  w += (size_t)128 * 512 * 2;
    p.WkvqT = (u16*)w;  w += (size_t)1536 * 512 * 2;
    p.WrT   = (u16*)w;  w += (size_t)512 * 512 * 2;
    p.WoT   = (u16*)w;  w += (size_t)512 * 512 * 2;
    p.kvb   = (u16*)w;  w += (size_t)4224 * 1024 * 2;
    p.hqb   = (u16*)w;  w += (size_t)4096 * 512 * 2;
    p.hrb   = (u16*)w;  w += (size_t)64 * 512 * 2;
    p.attnb = (u16*)w;  w += (size_t)4096 * 512 * 2;
    p.maskv = (float*)w;

    // Cooperative path: grid sized by the runtime's own occupancy model,
    // launch error-checked with full fallback.
    int bpc = 0;
    hipError_t err = hipOccupancyMaxActiveBlocksPerMultiprocessor(
        &bpc, reinterpret_cast<const void*>(fused_all), 256, 0);
    bool ok = (err == hipSuccess && bpc >= 1);
    if (ok) {
        int grid = bpc * 256;
        if (grid > 512) grid = 512;
        void* kargs[] = { (void*)&p };
        err = hipLaunchCooperativeKernel(reinterpret_cast<const void*>(fused_all),
                                         dim3(grid), dim3(256), kargs, 0, stream);
        ok = (err == hipSuccess);
    }
    if (!ok) {
        hipLaunchKernelGGL(k_prep, dim3(2589), dim3(256), 0, stream, p);
        hipLaunchKernelGGL(k_gB,   dim3(800),  dim3(256), 0, stream, p);
        hipLaunchKernelGGL(k_attn, dim3(512),  dim3(256), 0, stream, p);
        hipLaunchKernelGGL(k_gD,   dim3(256),  dim3(256), 0, stream, p);
    }
}

// Round 8
// 147.628 us; speedup vs baseline: 2.2793x; 2.2793x over previous
//
#include <hip/hip_runtime.h>
#include <cstdint>
#include <cstddef>

#define NH 8
#define DH 64
#define DM 512
#define CTX 64
#define BB 2
#define QL 2048
#define TT (QL + CTX - 1)   // 2111
#define HDIM 512
#define KVN 1024
#define KD 512

typedef unsigned short u16;
typedef __attribute__((ext_vector_type(8))) short bf16x8;
typedef __attribute__((ext_vector_type(4))) float f32x4;

__device__ __forceinline__ u16 f2bf(float f) {      // RNE float->bf16
    uint32_t u = __float_as_uint(f);
    u += 0x7FFF + ((u >> 16) & 1);
    return (u16)(u >> 16);
}

#define GLLDS(g, l) __builtin_amdgcn_global_load_lds( \
    (const __attribute__((address_space(1))) void*)(g), \
    (__attribute__((address_space(3))) void*)(l), 16, 0, 0)

struct Ptrs {
    const float *x, *r, *Wkv, *Wq, *bq, *Wr, *Wo;
    float* outp;
    u16 *xb, *WkvqT, *WoT, *kvb, *hqb, *hrb, *attnb;
    float* maskv;
};

// ---------------------------------------------------------------------------
// Prep kernel, one unit per block (2501 blocks):
//  [0,2111)      x cast -> xb bf16
//  [2111,2303)   Wkv/Wq transpose -> WkvqT (B^T bf16)
//  [2303,2367)   Wo transpose -> WoT
//  [2367,2375)   hr = r @ Wr (fp32 64x64 tile) -> hrb bf16
//  [2375,2501)   pad mask -> maskv
// ---------------------------------------------------------------------------
__global__ __launch_bounds__(256) void k_prep(Ptrs p)
{
    __shared__ __align__(16) char smem[16648];
    int bid = blockIdx.x;
    const int tid = threadIdx.x;

    if (bid < 2111) {                            // x cast
        int i = bid * 256 + tid;
        float4 v = ((const float4*)p.x)[i];
        ushort4 o; o.x = f2bf(v.x); o.y = f2bf(v.y); o.z = f2bf(v.z); o.w = f2bf(v.w);
        ((ushort4*)p.xb)[i] = o;
        return;
    }
    bid -= 2111;

    if (bid < 256) {                             // weight transposes (192 + 64)
        float (*tile)[65] = (float(*)[65])smem;
        const float* W; u16* WT; int N; int tidx;
        if (bid < 128)      { W = p.Wkv; WT = p.WkvqT;                      N = 1024; tidx = bid; }
        else if (bid < 192) { W = p.Wq;  WT = p.WkvqT + (size_t)1024 * 512; N = 512;  tidx = bid - 128; }
        else                { W = p.Wo;  WT = p.WoT;                        N = 512;  tidx = bid - 192; }
        const int tpr = N / 64;
        const int kb = (tidx / tpr) * 64, nbo = (tidx % tpr) * 64;
        const int c4 = (tid & 15) * 4;
        for (int kk = tid >> 4; kk < 64; kk += 16) {
            float4 v = *(const float4*)&W[(size_t)(kb + kk) * N + nbo + c4];
            tile[kk][c4 + 0] = v.x; tile[kk][c4 + 1] = v.y;
            tile[kk][c4 + 2] = v.z; tile[kk][c4 + 3] = v.w;
        }
        __syncthreads();
        for (int nn = tid >> 4; nn < 64; nn += 16) {
            ushort4 o;
            o.x = f2bf(tile[c4 + 0][nn]); o.y = f2bf(tile[c4 + 1][nn]);
            o.z = f2bf(tile[c4 + 2][nn]); o.w = f2bf(tile[c4 + 3][nn]);
            *(ushort4*)&WT[(size_t)(nbo + nn) * KD + kb + c4] = o;
        }
        return;
    }
    bid -= 256;

    if (bid < 8) {                               // hr fp32 GEMM: 64 x 64 tile
        float (*As)[68] = (float(*)[68])smem;                 // [16][68]
        float (*Bs)[68] = (float(*)[68])(smem + 4352);        // [16][68]
        const int tx = tid & 15, ty = tid >> 4;
        const int n0 = bid * 64;
        const int mloc = tid >> 2;
        const int ka4  = (tid & 3) * 4;
        const float* aptr = p.r + (size_t)mloc * KD + ka4;
        const int kb  = tid >> 4;
        const int nb4 = (tid & 15) * 4;
        const float* bptr = p.Wr + (size_t)kb * DM + n0 + nb4;

        float acc[4][4] = {};
        for (int kt = 0; kt < KD; kt += 16) {
            float4 av = *(const float4*)(aptr + kt);
            float4 bv = *(const float4*)(bptr + (size_t)kt * DM);
            __syncthreads();
            As[ka4 + 0][mloc] = av.x; As[ka4 + 1][mloc] = av.y;
            As[ka4 + 2][mloc] = av.z; As[ka4 + 3][mloc] = av.w;
            *(float4*)&Bs[kb][nb4] = bv;
            __syncthreads();
#pragma unroll
            for (int kk = 0; kk < 16; kk++) {
                float4 a = *(const float4*)&As[kk][ty * 4];
                float4 b = *(const float4*)&Bs[kk][tx * 4];
                acc[0][0] += a.x * b.x; acc[0][1] += a.x * b.y; acc[0][2] += a.x * b.z; acc[0][3] += a.x * b.w;
                acc[1][0] += a.y * b.x; acc[1][1] += a.y * b.y; acc[1][2] += a.y * b.z; acc[1][3] += a.y * b.w;
                acc[2][0] += a.z * b.x; acc[2][1] += a.z * b.y; acc[2][2] += a.z * b.z; acc[2][3] += a.z * b.w;
                acc[3][0] += a.w * b.x; acc[3][1] += a.w * b.y; acc[3][2] += a.w * b.z; acc[3][3] += a.w * b.w;
            }
        }
#pragma unroll
        for (int i = 0; i < 4; i++) {
            int m = ty * 4 + i;
            ushort4 o;
            o.x = f2bf(acc[i][0]); o.y = f2bf(acc[i][1]);
            o.z = f2bf(acc[i][2]); o.w = f2bf(acc[i][3]);
            *(ushort4*)&p.hrb[(size_t)m * HDIM + n0 + tx * 4] = o;
        }
        return;
    }
    bid -= 8;

    {                                            // pad mask (126 units)
        int* anyflag = (int*)smem;
        int t = bid >> 1, b = bid & 1;
        const float* row = p.x + (size_t)(b * TT + t) * DM;
        bool nz = (row[tid] != 0.f) || (row[tid + 256] != 0.f);
        if (tid == 0) *anyflag = 0;
        __syncthreads();
        unsigned long long bal = __ballot(nz);
        if ((tid & 63) == 0 && bal) atomicOr(anyflag, 1);
        __syncthreads();
        if (tid == 0) p.maskv[b * 64 + t] = *anyflag ? 0.f : -1e30f;
    }
}

// ---------------------------------------------------------------------------
// GEMM unit: 128(M) x 64(N) tile, BK=32, K=512, 256 threads.
// mode 1: G1 split epilogue (kv bf16 / hq+bq bf16 remapped)
// mode 3: G2 fp32 C
// ---------------------------------------------------------------------------
__device__ __forceinline__ void gemm_unit(
    const u16* __restrict__ A, const u16* __restrict__ BT,
    int m0, int n0, char* smem, int tid, int mode, const Ptrs& p)
{
    u16* As = (u16*)smem;            // 128*32
    u16* Bs = (u16*)(smem + 8192);   // 64*32
    const int lane = tid & 63;
    const int w    = tid >> 6;
    const int wm   = (w >> 1) * 64;
    const int wn   = (w & 1) * 32;

    const u16* ga0 = A  + (size_t)(m0 + (tid >> 2)) * KD + (tid & 3) * 8;
    const u16* ga1 = ga0 + (size_t)64 * KD;
    const u16* gb0 = BT + (size_t)(n0 + (tid >> 2)) * KD + (tid & 3) * 8;

    f32x4 acc[4][2];
#pragma unroll
    for (int i = 0; i < 4; i++)
#pragma unroll
        for (int j = 0; j < 2; j++)
            acc[i][j] = (f32x4){0.f, 0.f, 0.f, 0.f};

    const int fm = lane & 15;
    const int fk = (lane >> 4) * 8;

    for (int kt = 0; kt < KD; kt += 32) {
        __syncthreads();
        GLLDS(ga0 + kt, As + w * 512);
        GLLDS(ga1 + kt, As + 2048 + w * 512);
        GLLDS(gb0 + kt, Bs + w * 512);
        __syncthreads();

        bf16x8 af[4], bfr[2];
#pragma unroll
        for (int i = 0; i < 4; i++)
            af[i] = *(const bf16x8*)&As[(wm + i * 16 + fm) * 32 + fk];
#pragma unroll
        for (int j = 0; j < 2; j++)
            bfr[j] = *(const bf16x8*)&Bs[(wn + j * 16 + fm) * 32 + fk];
#pragma unroll
        for (int i = 0; i < 4; i++)
#pragma unroll
            for (int j = 0; j < 2; j++)
                acc[i][j] = __builtin_amdgcn_mfma_f32_16x16x32_bf16(af[i], bfr[j], acc[i][j], 0, 0, 0);
    }

    const int fc = lane & 15;
    const int fr = (lane >> 4) * 4;
    if (mode == 1) {
        const bool iskv = (n0 < 1024);
#pragma unroll
        for (int i = 0; i < 4; i++)
#pragma unroll
            for (int rr = 0; rr < 4; rr++) {
                int row = m0 + wm + i * 16 + fr + rr;
                if (row < BB * TT) {
                    if (iskv) {
#pragma unroll
                        for (int j = 0; j < 2; j++) {
                            int col = n0 + wn + j * 16 + fc;
                            p.kvb[(size_t)row * KVN + col] = f2bf(acc[i][j][rr]);
                        }
                    } else {
                        int bb = row / TT;
                        int t  = row - bb * TT;
                        if (t >= CTX - 1) {
                            size_t orow = (size_t)(bb * QL + t - (CTX - 1));
#pragma unroll
                            for (int j = 0; j < 2; j++) {
                                int col = n0 + wn + j * 16 + fc - 1024;
                                p.hqb[orow * HDIM + col] = f2bf(acc[i][j][rr] + p.bq[col]);
                            }
                        }
                    }
                }
            }
    } else {
#pragma unroll
        for (int i = 0; i < 4; i++)
#pragma unroll
            for (int rr = 0; rr < 4; rr++) {
                int row = m0 + wm + i * 16 + fr + rr;
#pragma unroll
                for (int j = 0; j < 2; j++) {
                    int col = n0 + wn + j * 16 + fc;
                    p.outp[(size_t)row * DM + col] = acc[i][j][rr];
                }
            }
    }
}

// G1: 792 blocks (33 m-tiles x 24 n-tiles of 128x64)
__global__ __launch_bounds__(256) void k_g1(Ptrs p)
{
    __shared__ __align__(16) char smem[12288];
    int u = blockIdx.x;
    int mu = u / 24, nu = u - mu * 24;
    gemm_unit(p.xb, p.WkvqT, mu * 128, nu * 64, smem, threadIdx.x, 1, p);
}

// G2: 256 blocks (32 m-tiles x 8 n-tiles of 128x64)
__global__ __launch_bounds__(256) void k_g2(Ptrs p)
{
    __shared__ __align__(16) char smem[12288];
    int u = blockIdx.x;
    gemm_unit(p.attnb, p.WoT, (u >> 3) * 128, (u & 7) * 64, smem, threadIdx.x, 3, p);
}

// ---------------------------------------------------------------------------
// MFMA sliding-window relative attention (verified Round-5 structure).
// ---------------------------------------------------------------------------
__global__ __launch_bounds__(256, 2) void k_attn(Ptrs p)
{
    __shared__ __align__(16) char smem[55296];
    float* sprime = (float*)smem;                 // [4][16][80]
    u16*   vTs    = (u16*)smem;                   // [64][136] (aliases sprime)
    float* s2s    = (float*)(smem + 20480);       // [4][16][68]
    u16*   wband  = (u16*)(smem + 37888);         // [64][136]

    const int u = blockIdx.x;
    const int q0 = (u & 31) * 64;
    const int h  = (u >> 5) & 7;
    const int b  = u >> 8;
    const int tid  = threadIdx.x;
    const int lane = tid & 63;
    const int w    = tid >> 6;
    const int qb   = q0 + w * 16;

    {
        uint32_t* wz = (uint32_t*)wband;
#pragma unroll
        for (int i = 0; i < 17; i++) wz[tid + i * 256] = 0;
    }
    __syncthreads();

    const int fm = lane & 15;
    const int fk = (lane >> 4) * 8;

    const u16* hqrow = p.hqb + (size_t)(b * QL + qb + fm) * HDIM + h * DH + fk;
    bf16x8 afr0 = *(const bf16x8*)(hqrow);
    bf16x8 afr1 = *(const bf16x8*)(hqrow + 32);

    // QK': S'[16 x 80]
    {
        const u16* kbase = p.kvb + (size_t)(b * TT + qb + fm) * KVN + h * DH + fk;
#pragma unroll
        for (int nt = 0; nt < 5; nt++) {
            bf16x8 b0 = *(const bf16x8*)(kbase + (size_t)nt * 16 * KVN);
            bf16x8 b1 = *(const bf16x8*)(kbase + (size_t)nt * 16 * KVN + 32);
            f32x4 acc = (f32x4){0.f, 0.f, 0.f, 0.f};
            acc = __builtin_amdgcn_mfma_f32_16x16x32_bf16(afr0, b0, acc, 0, 0, 0);
            acc = __builtin_amdgcn_mfma_f32_16x16x32_bf16(afr1, b1, acc, 0, 0, 0);
            const int row = (lane >> 4) * 4;
#pragma unroll
            for (int rr = 0; rr < 4; rr++)
                sprime[w * 1280 + (row + rr) * 80 + nt * 16 + fm] = acc[rr];
        }
    }
    // S2[16 x 64] = hq @ hr^T
    {
        const u16* hrbase = p.hrb + (size_t)fm * HDIM + h * DH + fk;
#pragma unroll
        for (int nc = 0; nc < 4; nc++) {
            bf16x8 b0 = *(const bf16x8*)(hrbase + (size_t)nc * 16 * HDIM);
            bf16x8 b1 = *(const bf16x8*)(hrbase + (size_t)nc * 16 * HDIM + 32);
            f32x4 acc = (f32x4){0.f, 0.f, 0.f, 0.f};
            acc = __builtin_amdgcn_mfma_f32_16x16x32_bf16(afr0, b0, acc, 0, 0, 0);
            acc = __builtin_amdgcn_mfma_f32_16x16x32_bf16(afr1, b1, acc, 0, 0, 0);
            const int row = (lane >> 4) * 4;
#pragma unroll
            for (int rr = 0; rr < 4; rr++)
                s2s[w * 1088 + (row + rr) * 68 + nc * 16 + fm] = acc[rr];
        }
    }

    // softmax
#pragma unroll 1
    for (int i = 0; i < 16; i++) {
        const int qloc = w * 16 + i;
        float s = (sprime[w * 1280 + i * 80 + i + lane] +
                   s2s[w * 1088 + i * 68 + lane]) * 0.125f;
        if (q0 == 0) {
            int t = qloc + lane;
            if (t < 63) s += p.maskv[b * 64 + t];
        }
        float mx = s;
#pragma unroll
        for (int off = 32; off; off >>= 1) mx = fmaxf(mx, __shfl_xor(mx, off, 64));
        float e = __expf(s - mx);
        float sum = e;
#pragma unroll
        for (int off = 32; off; off >>= 1) sum += __shfl_xor(sum, off, 64);
        wband[qloc * 136 + qloc + lane] = f2bf(e / sum);
    }
    __syncthreads();

    // stage vT[d][t]
    {
        const int r0 = tid >> 4;
        const int c4 = (tid & 15) * 4;
        for (int rr = r0; rr < 127; rr += 16) {
            ushort4 vv = *(const ushort4*)&p.kvb[(size_t)(b * TT + q0 + rr) * KVN + HDIM + h * DH + c4];
            vTs[(c4 + 0) * 136 + rr] = vv.x;
            vTs[(c4 + 1) * 136 + rr] = vv.y;
            vTs[(c4 + 2) * 136 + rr] = vv.z;
            vTs[(c4 + 3) * 136 + rr] = vv.w;
        }
        if (tid < 64) vTs[tid * 136 + 127] = 0;
    }
    __syncthreads();

    // PV
    f32x4 oacc[4];
#pragma unroll
    for (int j = 0; j < 4; j++) oacc[j] = (f32x4){0.f, 0.f, 0.f, 0.f};
#pragma unroll
    for (int ks = 0; ks < 4; ks++) {
        bf16x8 wa = *(const bf16x8*)&wband[(w * 16 + fm) * 136 + ks * 32 + fk];
#pragma unroll
        for (int j = 0; j < 4; j++) {
            bf16x8 vb = *(const bf16x8*)&vTs[(j * 16 + fm) * 136 + ks * 32 + fk];
            oacc[j] = __builtin_amdgcn_mfma_f32_16x16x32_bf16(wa, vb, oacc[j], 0, 0, 0);
        }
    }
    {
        const int row = (lane >> 4) * 4;
#pragma unroll
        for (int j = 0; j < 4; j++)
#pragma unroll
            for (int rr = 0; rr < 4; rr++)
                p.attnb[(size_t)(b * QL + qb + row + rr) * HDIM + h * DH + j * 16 + fm] =
                    f2bf(oacc[j][rr]);
    }
}

// ---------------------------------------------------------------------------
extern "C" void kernel_launch(void* const* d_in, const int* in_sizes, int n_in,
                              void* d_out, int out_size, void* d_ws, size_t ws_size,
                              hipStream_t stream)
{
    Ptrs p;
    p.x   = (const float*)d_in[0];
    p.r   = (const float*)d_in[1];
    p.Wkv = (const float*)d_in[2];
    p.Wq  = (const float*)d_in[3];
    p.bq  = (const float*)d_in[4];
    p.Wr  = (const float*)d_in[5];
    p.Wo  = (const float*)d_in[6];
    p.outp = (float*)d_out;

    char* w = (char*)d_ws;
    p.xb    = (u16*)w;  w += (size_t)4224 * 512 * 2;
    p.WkvqT = (u16*)w;  w += (size_t)1536 * 512 * 2;
    p.WoT   = (u16*)w;  w += (size_t)512 * 512 * 2;
    p.kvb   = (u16*)w;  w += (size_t)4224 * 1024 * 2;
    p.hqb   = (u16*)w;  w += (size_t)4096 * 512 * 2;
    p.hrb   = (u16*)w;  w += (size_t)64 * 512 * 2;
    p.attnb = (u16*)w;  w += (size_t)4096 * 512 * 2;
    p.maskv = (float*)w;

    hipLaunchKernelGGL(k_prep, dim3(2501), dim3(256), 0, stream, p);
    hipLaunchKernelGGL(k_g1,   dim3(792),  dim3(256), 0, stream, p);
    hipLaunchKernelGGL(k_attn, dim3(512),  dim3(256), 0, stream, p);
    hipLaunchKernelGGL(k_g2,   dim3(256),  dim3(256), 0, stream, p);
}

// Round 9
// 146.168 us; speedup vs baseline: 2.3020x; 1.0100x over previous
//
#include <hip/hip_runtime.h>
#include <cstdint>
#include <cstddef>

#define NH 8
#define DH 64
#define DM 512
#define CTX 64
#define BB 2
#define QL 2048
#define TT (QL + CTX - 1)   // 2111
#define HDIM 512
#define KVN 1024
#define KD 512

typedef unsigned short u16;
typedef __attribute__((ext_vector_type(8))) short bf16x8;
typedef __attribute__((ext_vector_type(4))) float f32x4;

__device__ __forceinline__ u16 f2bf(float f) {      // RNE float->bf16
    uint32_t u = __float_as_uint(f);
    u += 0x7FFF + ((u >> 16) & 1);
    return (u16)(u >> 16);
}

#define GLLDS(g, l) __builtin_amdgcn_global_load_lds( \
    (const __attribute__((address_space(1))) void*)(g), \
    (__attribute__((address_space(3))) void*)(l), 16, 0, 0)

struct Ptrs {
    const float *x, *r, *Wkv, *Wq, *bq, *Wr, *Wo;
    float* outp;
    u16 *xb, *WkvqT, *WoT, *kvb, *hqb, *hrb, *attnb;
    float* maskv;
};

// ---------------------------------------------------------------------------
// Prep kernel, one unit per block (2501 blocks):
//  [0,2111)      x cast -> xb bf16
//  [2111,2367)   Wkv/Wq/Wo transpose -> WkvqT / WoT (B^T bf16)
//  [2367,2375)   hr = r @ Wr (fp32 64x64 tile) -> hrb bf16 row-major
//  [2375,2501)   pad mask -> maskv
// ---------------------------------------------------------------------------
__global__ __launch_bounds__(256) void k_prep(Ptrs p)
{
    __shared__ __align__(16) char smem[16648];
    int bid = blockIdx.x;
    const int tid = threadIdx.x;

    if (bid < 2111) {                            // x cast
        int i = bid * 256 + tid;
        float4 v = ((const float4*)p.x)[i];
        ushort4 o; o.x = f2bf(v.x); o.y = f2bf(v.y); o.z = f2bf(v.z); o.w = f2bf(v.w);
        ((ushort4*)p.xb)[i] = o;
        return;
    }
    bid -= 2111;

    if (bid < 256) {                             // weight transposes (192 + 64)
        float (*tile)[65] = (float(*)[65])smem;
        const float* W; u16* WT; int N; int tidx;
        if (bid < 128)      { W = p.Wkv; WT = p.WkvqT;                      N = 1024; tidx = bid; }
        else if (bid < 192) { W = p.Wq;  WT = p.WkvqT + (size_t)1024 * 512; N = 512;  tidx = bid - 128; }
        else                { W = p.Wo;  WT = p.WoT;                        N = 512;  tidx = bid - 192; }
        const int tpr = N / 64;
        const int kb = (tidx / tpr) * 64, nbo = (tidx % tpr) * 64;
        const int c4 = (tid & 15) * 4;
        for (int kk = tid >> 4; kk < 64; kk += 16) {
            float4 v = *(const float4*)&W[(size_t)(kb + kk) * N + nbo + c4];
            tile[kk][c4 + 0] = v.x; tile[kk][c4 + 1] = v.y;
            tile[kk][c4 + 2] = v.z; tile[kk][c4 + 3] = v.w;
        }
        __syncthreads();
        for (int nn = tid >> 4; nn < 64; nn += 16) {
            ushort4 o;
            o.x = f2bf(tile[c4 + 0][nn]); o.y = f2bf(tile[c4 + 1][nn]);
            o.z = f2bf(tile[c4 + 2][nn]); o.w = f2bf(tile[c4 + 3][nn]);
            *(ushort4*)&WT[(size_t)(nbo + nn) * KD + kb + c4] = o;
        }
        return;
    }
    bid -= 256;

    if (bid < 8) {                               // hr fp32 GEMM: 64 x 64 tile
        float (*As)[68] = (float(*)[68])smem;                 // [16][68]
        float (*Bs)[68] = (float(*)[68])(smem + 4352);        // [16][68]
        const int tx = tid & 15, ty = tid >> 4;
        const int n0 = bid * 64;
        const int mloc = tid >> 2;
        const int ka4  = (tid & 3) * 4;
        const float* aptr = p.r + (size_t)mloc * KD + ka4;
        const int kb  = tid >> 4;
        const int nb4 = (tid & 15) * 4;
        const float* bptr = p.Wr + (size_t)kb * DM + n0 + nb4;

        float acc[4][4] = {};
        for (int kt = 0; kt < KD; kt += 16) {
            float4 av = *(const float4*)(aptr + kt);
            float4 bv = *(const float4*)(bptr + (size_t)kt * DM);
            __syncthreads();
            As[ka4 + 0][mloc] = av.x; As[ka4 + 1][mloc] = av.y;
            As[ka4 + 2][mloc] = av.z; As[ka4 + 3][mloc] = av.w;
            *(float4*)&Bs[kb][nb4] = bv;
            __syncthreads();
#pragma unroll
            for (int kk = 0; kk < 16; kk++) {
                float4 a = *(const float4*)&As[kk][ty * 4];
                float4 b = *(const float4*)&Bs[kk][tx * 4];
                acc[0][0] += a.x * b.x; acc[0][1] += a.x * b.y; acc[0][2] += a.x * b.z; acc[0][3] += a.x * b.w;
                acc[1][0] += a.y * b.x; acc[1][1] += a.y * b.y; acc[1][2] += a.y * b.z; acc[1][3] += a.y * b.w;
                acc[2][0] += a.z * b.x; acc[2][1] += a.z * b.y; acc[2][2] += a.z * b.z; acc[2][3] += a.z * b.w;
                acc[3][0] += a.w * b.x; acc[3][1] += a.w * b.y; acc[3][2] += a.w * b.z; acc[3][3] += a.w * b.w;
            }
        }
#pragma unroll
        for (int i = 0; i < 4; i++) {
            int m = ty * 4 + i;
            ushort4 o;
            o.x = f2bf(acc[i][0]); o.y = f2bf(acc[i][1]);
            o.z = f2bf(acc[i][2]); o.w = f2bf(acc[i][3]);
            *(ushort4*)&p.hrb[(size_t)m * HDIM + n0 + tx * 4] = o;
        }
        return;
    }
    bid -= 8;

    {                                            // pad mask (126 units)
        int* anyflag = (int*)smem;
        int t = bid >> 1, b = bid & 1;
        const float* row = p.x + (size_t)(b * TT + t) * DM;
        bool nz = (row[tid] != 0.f) || (row[tid + 256] != 0.f);
        if (tid == 0) *anyflag = 0;
        __syncthreads();
        unsigned long long bal = __ballot(nz);
        if ((tid & 63) == 0 && bal) atomicOr(anyflag, 1);
        __syncthreads();
        if (tid == 0) p.maskv[b * 64 + t] = *anyflag ? 0.f : -1e30f;
    }
}

// ---------------------------------------------------------------------------
// G1: bf16 MFMA GEMM 128x128 (m97 structure), split epilogue.
// [kv|hq] = xb @ [Wkv|Wq]^T. 396 blocks (12 n-tiles x 33 m-tiles).
// ---------------------------------------------------------------------------
__global__ __launch_bounds__(256) void k_g1(Ptrs p)
{
    __shared__ u16 As[128 * 32];
    __shared__ u16 Bs[128 * 32];

    const int tid  = threadIdx.x;
    const int lane = tid & 63;
    const int w    = tid >> 6;
    const int wm   = (w >> 1) * 64;
    const int wn   = (w & 1) * 64;
    const int m0   = blockIdx.y * 128;
    const int n0   = blockIdx.x * 128;

    const u16* ga0 = p.xb    + (size_t)(m0 + (tid >> 2)) * KD + (tid & 3) * 8;
    const u16* ga1 = ga0 + (size_t)64 * KD;
    const u16* gb0 = p.WkvqT + (size_t)(n0 + (tid >> 2)) * KD + (tid & 3) * 8;
    const u16* gb1 = gb0 + (size_t)64 * KD;

    f32x4 acc[4][4];
#pragma unroll
    for (int i = 0; i < 4; i++)
#pragma unroll
        for (int j = 0; j < 4; j++)
            acc[i][j] = (f32x4){0.f, 0.f, 0.f, 0.f};

    const int fm = lane & 15;
    const int fk = (lane >> 4) * 8;

    for (int kt = 0; kt < KD; kt += 32) {
        __syncthreads();
        GLLDS(ga0 + kt, &As[w * 512]);
        GLLDS(ga1 + kt, &As[2048 + w * 512]);
        GLLDS(gb0 + kt, &Bs[w * 512]);
        GLLDS(gb1 + kt, &Bs[2048 + w * 512]);
        __syncthreads();

        bf16x8 af[4], bfr[4];
#pragma unroll
        for (int i = 0; i < 4; i++)
            af[i] = *(const bf16x8*)&As[(wm + i * 16 + fm) * 32 + fk];
#pragma unroll
        for (int j = 0; j < 4; j++)
            bfr[j] = *(const bf16x8*)&Bs[(wn + j * 16 + fm) * 32 + fk];
#pragma unroll
        for (int i = 0; i < 4; i++)
#pragma unroll
            for (int j = 0; j < 4; j++)
                acc[i][j] = __builtin_amdgcn_mfma_f32_16x16x32_bf16(af[i], bfr[j], acc[i][j], 0, 0, 0);
    }

    const int fc = lane & 15;
    const int fr = (lane >> 4) * 4;
    const bool iskv = (n0 < 1024);
#pragma unroll
    for (int i = 0; i < 4; i++)
#pragma unroll
        for (int rr = 0; rr < 4; rr++) {
            int row = m0 + wm + i * 16 + fr + rr;
            if (row < BB * TT) {
                if (iskv) {
#pragma unroll
                    for (int j = 0; j < 4; j++) {
                        int col = n0 + wn + j * 16 + fc;
                        p.kvb[(size_t)row * KVN + col] = f2bf(acc[i][j][rr]);
                    }
                } else {
                    int bb = row / TT;
                    int t  = row - bb * TT;
                    if (t >= CTX - 1) {
                        size_t orow = (size_t)(bb * QL + t - (CTX - 1));
#pragma unroll
                        for (int j = 0; j < 4; j++) {
                            int col = n0 + wn + j * 16 + fc - 1024;
                            p.hqb[orow * HDIM + col] = f2bf(acc[i][j][rr] + p.bq[col]);
                        }
                    }
                }
            }
        }
}

// ---------------------------------------------------------------------------
// G2: bf16 MFMA GEMM 128(M)x64(N), fp32 out. 256 blocks.
// ---------------------------------------------------------------------------
__global__ __launch_bounds__(256) void k_g2(Ptrs p)
{
    __shared__ u16 As[128 * 32];
    __shared__ u16 Bs[64 * 32];

    const int tid  = threadIdx.x;
    const int lane = tid & 63;
    const int w    = tid >> 6;
    const int wm   = (w >> 1) * 64;
    const int wn   = (w & 1) * 32;
    const int m0   = (blockIdx.x >> 3) * 128;
    const int n0   = (blockIdx.x & 7) * 64;

    const u16* ga0 = p.attnb + (size_t)(m0 + (tid >> 2)) * KD + (tid & 3) * 8;
    const u16* ga1 = ga0 + (size_t)64 * KD;
    const u16* gb0 = p.WoT + (size_t)(n0 + (tid >> 2)) * KD + (tid & 3) * 8;

    f32x4 acc[4][2];
#pragma unroll
    for (int i = 0; i < 4; i++)
#pragma unroll
        for (int j = 0; j < 2; j++)
            acc[i][j] = (f32x4){0.f, 0.f, 0.f, 0.f};

    const int fm = lane & 15;
    const int fk = (lane >> 4) * 8;

    for (int kt = 0; kt < KD; kt += 32) {
        __syncthreads();
        GLLDS(ga0 + kt, &As[w * 512]);
        GLLDS(ga1 + kt, &As[2048 + w * 512]);
        GLLDS(gb0 + kt, &Bs[w * 512]);
        __syncthreads();

        bf16x8 af[4], bfr[2];
#pragma unroll
        for (int i = 0; i < 4; i++)
            af[i] = *(const bf16x8*)&As[(wm + i * 16 + fm) * 32 + fk];
#pragma unroll
        for (int j = 0; j < 2; j++)
            bfr[j] = *(const bf16x8*)&Bs[(wn + j * 16 + fm) * 32 + fk];
#pragma unroll
        for (int i = 0; i < 4; i++)
#pragma unroll
            for (int j = 0; j < 2; j++)
                acc[i][j] = __builtin_amdgcn_mfma_f32_16x16x32_bf16(af[i], bfr[j], acc[i][j], 0, 0, 0);
    }

    const int fc = lane & 15;
    const int fr = (lane >> 4) * 4;
#pragma unroll
    for (int i = 0; i < 4; i++)
#pragma unroll
        for (int rr = 0; rr < 4; rr++) {
            int row = m0 + wm + i * 16 + fr + rr;
#pragma unroll
            for (int j = 0; j < 2; j++) {
                int col = n0 + wn + j * 16 + fc;
                p.outp[(size_t)row * DM + col] = acc[i][j][rr];
            }
        }
}

// ---------------------------------------------------------------------------
// MFMA sliding-window relative attention (verified Round-5 structure).
// ---------------------------------------------------------------------------
__global__ __launch_bounds__(256, 2) void k_attn(Ptrs p)
{
    __shared__ __align__(16) char smem[55296];
    float* sprime = (float*)smem;                 // [4][16][80]
    u16*   vTs    = (u16*)smem;                   // [64][136] (aliases sprime)
    float* s2s    = (float*)(smem + 20480);       // [4][16][68]
    u16*   wband  = (u16*)(smem + 37888);         // [64][136]

    const int u = blockIdx.x;
    const int q0 = (u & 31) * 64;
    const int h  = (u >> 5) & 7;
    const int b  = u >> 8;
    const int tid  = threadIdx.x;
    const int lane = tid & 63;
    const int w    = tid >> 6;
    const int qb   = q0 + w * 16;

    {
        uint32_t* wz = (uint32_t*)wband;
#pragma unroll
        for (int i = 0; i < 17; i++) wz[tid + i * 256] = 0;
    }
    __syncthreads();

    const int fm = lane & 15;
    const int fk = (lane >> 4) * 8;

    const u16* hqrow = p.hqb + (size_t)(b * QL + qb + fm) * HDIM + h * DH + fk;
    bf16x8 afr0 = *(const bf16x8*)(hqrow);
    bf16x8 afr1 = *(const bf16x8*)(hqrow + 32);

    // QK': S'[16 x 80]
    {
        const u16* kbase = p.kvb + (size_t)(b * TT + qb + fm) * KVN + h * DH + fk;
#pragma unroll
        for (int nt = 0; nt < 5; nt++) {
            bf16x8 b0 = *(const bf16x8*)(kbase + (size_t)nt * 16 * KVN);
            bf16x8 b1 = *(const bf16x8*)(kbase + (size_t)nt * 16 * KVN + 32);
            f32x4 acc = (f32x4){0.f, 0.f, 0.f, 0.f};
            acc = __builtin_amdgcn_mfma_f32_16x16x32_bf16(afr0, b0, acc, 0, 0, 0);
            acc = __builtin_amdgcn_mfma_f32_16x16x32_bf16(afr1, b1, acc, 0, 0, 0);
            const int row = (lane >> 4) * 4;
#pragma unroll
            for (int rr = 0; rr < 4; rr++)
                sprime[w * 1280 + (row + rr) * 80 + nt * 16 + fm] = acc[rr];
        }
    }
    // S2[16 x 64] = hq @ hr^T
    {
        const u16* hrbase = p.hrb + (size_t)fm * HDIM + h * DH + fk;
#pragma unroll
        for (int nc = 0; nc < 4; nc++) {
            bf16x8 b0 = *(const bf16x8*)(hrbase + (size_t)nc * 16 * HDIM);
            bf16x8 b1 = *(const bf16x8*)(hrbase + (size_t)nc * 16 * HDIM + 32);
            f32x4 acc = (f32x4){0.f, 0.f, 0.f, 0.f};
            acc = __builtin_amdgcn_mfma_f32_16x16x32_bf16(afr0, b0, acc, 0, 0, 0);
            acc = __builtin_amdgcn_mfma_f32_16x16x32_bf16(afr1, b1, acc, 0, 0, 0);
            const int row = (lane >> 4) * 4;
#pragma unroll
            for (int rr = 0; rr < 4; rr++)
                s2s[w * 1088 + (row + rr) * 68 + nc * 16 + fm] = acc[rr];
        }
    }

    // softmax
#pragma unroll 1
    for (int i = 0; i < 16; i++) {
        const int qloc = w * 16 + i;
        float s = (sprime[w * 1280 + i * 80 + i + lane] +
                   s2s[w * 1088 + i * 68 + lane]) * 0.125f;
        if (q0 == 0) {
            int t = qloc + lane;
            if (t < 63) s += p.maskv[b * 64 + t];
        }
        float mx = s;
#pragma unroll
        for (int off = 32; off; off >>= 1) mx = fmaxf(mx, __shfl_xor(mx, off, 64));
        float e = __expf(s - mx);
        float sum = e;
#pragma unroll
        for (int off = 32; off; off >>= 1) sum += __shfl_xor(sum, off, 64);
        wband[qloc * 136 + qloc + lane] = f2bf(e / sum);
    }
    __syncthreads();

    // stage vT[d][t]
    {
        const int r0 = tid >> 4;
        const int c4 = (tid & 15) * 4;
        for (int rr = r0; rr < 127; rr += 16) {
            ushort4 vv = *(const ushort4*)&p.kvb[(size_t)(b * TT + q0 + rr) * KVN + HDIM + h * DH + c4];
            vTs[(c4 + 0) * 136 + rr] = vv.x;
            vTs[(c4 + 1) * 136 + rr] = vv.y;
            vTs[(c4 + 2) * 136 + rr] = vv.z;
            vTs[(c4 + 3) * 136 + rr] = vv.w;
        }
        if (tid < 64) vTs[tid * 136 + 127] = 0;
    }
    __syncthreads();

    // PV
    f32x4 oacc[4];
#pragma unroll
    for (int j = 0; j < 4; j++) oacc[j] = (f32x4){0.f, 0.f, 0.f, 0.f};
#pragma unroll
    for (int ks = 0; ks < 4; ks++) {
        bf16x8 wa = *(const bf16x8*)&wband[(w * 16 + fm) * 136 + ks * 32 + fk];
#pragma unroll
        for (int j = 0; j < 4; j++) {
            bf16x8 vb = *(const bf16x8*)&vTs[(j * 16 + fm) * 136 + ks * 32 + fk];
            oacc[j] = __builtin_amdgcn_mfma_f32_16x16x32_bf16(wa, vb, oacc[j], 0, 0, 0);
        }
    }
    {
        const int row = (lane >> 4) * 4;
#pragma unroll
        for (int j = 0; j < 4; j++)
#pragma unroll
            for (int rr = 0; rr < 4; rr++)
                p.attnb[(size_t)(b * QL + qb + row + rr) * HDIM + h * DH + j * 16 + fm] =
                    f2bf(oacc[j][rr]);
    }
}

// ---------------------------------------------------------------------------
extern "C" void kernel_launch(void* const* d_in, const int* in_sizes, int n_in,
                              void* d_out, int out_size, void* d_ws, size_t ws_size,
                              hipStream_t stream)
{
    Ptrs p;
    p.x   = (const float*)d_in[0];
    p.r   = (const float*)d_in[1];
    p.Wkv = (const float*)d_in[2];
    p.Wq  = (const float*)d_in[3];
    p.bq  = (const float*)d_in[4];
    p.Wr  = (const float*)d_in[5];
    p.Wo  = (const float*)d_in[6];
    p.outp = (float*)d_out;

    char* w = (char*)d_ws;
    p.xb    = (u16*)w;  w += (size_t)4224 * 512 * 2;
    p.WkvqT = (u16*)w;  w += (size_t)1536 * 512 * 2;
    p.WoT   = (u16*)w;  w += (size_t)512 * 512 * 2;
    p.kvb   = (u16*)w;  w += (size_t)4224 * 1024 * 2;
    p.hqb   = (u16*)w;  w += (size_t)4096 * 512 * 2;
    p.hrb   = (u16*)w;  w += (size_t)64 * 512 * 2;
    p.attnb = (u16*)w;  w += (size_t)4096 * 512 * 2;
    p.maskv = (float*)w;

    hipLaunchKernelGGL(k_prep, dim3(2501),   dim3(256), 0, stream, p);
    hipLaunchKernelGGL(k_g1,   dim3(12, 33), dim3(256), 0, stream, p);
    hipLaunchKernelGGL(k_attn, dim3(512),    dim3(256), 0, stream, p);
    hipLaunchKernelGGL(k_g2,   dim3(256),    dim3(256), 0, stream, p);
}

// Round 10
// 143.247 us; speedup vs baseline: 2.3490x; 1.0204x over previous
//
#include <hip/hip_runtime.h>
#include <cstdint>
#include <cstddef>

#define NH 8
#define DH 64
#define DM 512
#define CTX 64
#define BB 2
#define QL 2048
#define TT (QL + CTX - 1)   // 2111
#define HDIM 512
#define KVN 1024
#define KD 512

typedef unsigned short u16;
typedef __attribute__((ext_vector_type(8))) short bf16x8;
typedef __attribute__((ext_vector_type(4))) float f32x4;

__device__ __forceinline__ u16 f2bf(float f) {      // RNE float->bf16
    uint32_t u = __float_as_uint(f);
    u += 0x7FFF + ((u >> 16) & 1);
    return (u16)(u >> 16);
}

#define GLLDS(g, l) __builtin_amdgcn_global_load_lds( \
    (const __attribute__((address_space(1))) void*)(g), \
    (__attribute__((address_space(3))) void*)(l), 16, 0, 0)

struct Ptrs {
    const float *x, *r, *Wkv, *Wq, *bq, *Wr, *Wo;
    float* outp;
    u16 *xb, *WkvqT, *WoT, *kvb, *hqb, *hrb, *attnb;
    float* maskv;
};

// ---------------------------------------------------------------------------
// Prep kernel, one unit per block (2525 blocks):
//  [0,2111)      x cast -> xb bf16
//  [2111,2367)   Wkv/Wq/Wo transpose -> WkvqT / WoT (B^T bf16)
//  [2367,2399)   hr = r @ Wr: 32 blocks of 64x16 fp32 tiles -> hrb bf16
//  [2399,2525)   pad mask -> maskv
// ---------------------------------------------------------------------------
__global__ __launch_bounds__(256) void k_prep(Ptrs p)
{
    __shared__ __align__(16) char smem[16648];
    int bid = blockIdx.x;
    const int tid = threadIdx.x;

    if (bid < 2111) {                            // x cast
        int i = bid * 256 + tid;
        float4 v = ((const float4*)p.x)[i];
        ushort4 o; o.x = f2bf(v.x); o.y = f2bf(v.y); o.z = f2bf(v.z); o.w = f2bf(v.w);
        ((ushort4*)p.xb)[i] = o;
        return;
    }
    bid -= 2111;

    if (bid < 256) {                             // weight transposes (192 + 64)
        float (*tile)[65] = (float(*)[65])smem;
        const float* W; u16* WT; int N; int tidx;
        if (bid < 128)      { W = p.Wkv; WT = p.WkvqT;                      N = 1024; tidx = bid; }
        else if (bid < 192) { W = p.Wq;  WT = p.WkvqT + (size_t)1024 * 512; N = 512;  tidx = bid - 128; }
        else                { W = p.Wo;  WT = p.WoT;                        N = 512;  tidx = bid - 192; }
        const int tpr = N / 64;
        const int kb = (tidx / tpr) * 64, nbo = (tidx % tpr) * 64;
        const int c4 = (tid & 15) * 4;
        for (int kk = tid >> 4; kk < 64; kk += 16) {
            float4 v = *(const float4*)&W[(size_t)(kb + kk) * N + nbo + c4];
            tile[kk][c4 + 0] = v.x; tile[kk][c4 + 1] = v.y;
            tile[kk][c4 + 2] = v.z; tile[kk][c4 + 3] = v.w;
        }
        __syncthreads();
        for (int nn = tid >> 4; nn < 64; nn += 16) {
            ushort4 o;
            o.x = f2bf(tile[c4 + 0][nn]); o.y = f2bf(tile[c4 + 1][nn]);
            o.z = f2bf(tile[c4 + 2][nn]); o.w = f2bf(tile[c4 + 3][nn]);
            *(ushort4*)&WT[(size_t)(nbo + nn) * KD + kb + c4] = o;
        }
        return;
    }
    bid -= 256;

    if (bid < 32) {                              // hr fp32 GEMM: 64 x 16 tile
        float (*As)[68] = (float(*)[68])smem;                 // [16][68]
        float (*Bs)[20] = (float(*)[20])(smem + 4352);        // [16][20]
        const int tx = tid & 15;      // col within tile
        const int ty = tid >> 4;      // m-group (4 rows each) / also Bs k-row
        const int n0 = bid * 16;
        const int mloc = tid >> 2;    // A-stage row 0..63
        const int ka4  = (tid & 3) * 4;
        const float* aptr = p.r + (size_t)mloc * KD + ka4;
        const float* bptr = p.Wr + (size_t)ty * DM + n0 + tx;

        float acc[4] = {};
        for (int kt = 0; kt < KD; kt += 16) {
            float4 av = *(const float4*)(aptr + kt);
            float  bv = bptr[(size_t)kt * DM];
            __syncthreads();
            As[ka4 + 0][mloc] = av.x; As[ka4 + 1][mloc] = av.y;
            As[ka4 + 2][mloc] = av.z; As[ka4 + 3][mloc] = av.w;
            Bs[ty][tx] = bv;
            __syncthreads();
#pragma unroll
            for (int kk = 0; kk < 16; kk++) {
                float4 a = *(const float4*)&As[kk][ty * 4];
                float  b = Bs[kk][tx];
                acc[0] += a.x * b; acc[1] += a.y * b;
                acc[2] += a.z * b; acc[3] += a.w * b;
            }
        }
#pragma unroll
        for (int i = 0; i < 4; i++)
            p.hrb[(size_t)(ty * 4 + i) * HDIM + n0 + tx] = f2bf(acc[i]);
        return;
    }
    bid -= 32;

    {                                            // pad mask (126 units)
        int* anyflag = (int*)smem;
        int t = bid >> 1, b = bid & 1;
        const float* row = p.x + (size_t)(b * TT + t) * DM;
        bool nz = (row[tid] != 0.f) || (row[tid + 256] != 0.f);
        if (tid == 0) *anyflag = 0;
        __syncthreads();
        unsigned long long bal = __ballot(nz);
        if ((tid & 63) == 0 && bal) atomicOr(anyflag, 1);
        __syncthreads();
        if (tid == 0) p.maskv[b * 64 + t] = *anyflag ? 0.f : -1e30f;
    }
}

// ---------------------------------------------------------------------------
// G1: bf16 MFMA GEMM 128x128 (m97 structure), split epilogue.
// [kv|hq] = xb @ [Wkv|Wq]^T. 396 blocks (12 n-tiles x 33 m-tiles).
// ---------------------------------------------------------------------------
__global__ __launch_bounds__(256) void k_g1(Ptrs p)
{
    __shared__ u16 As[128 * 32];
    __shared__ u16 Bs[128 * 32];

    const int tid  = threadIdx.x;
    const int lane = tid & 63;
    const int w    = tid >> 6;
    const int wm   = (w >> 1) * 64;
    const int wn   = (w & 1) * 64;
    const int m0   = blockIdx.y * 128;
    const int n0   = blockIdx.x * 128;

    const u16* ga0 = p.xb    + (size_t)(m0 + (tid >> 2)) * KD + (tid & 3) * 8;
    const u16* ga1 = ga0 + (size_t)64 * KD;
    const u16* gb0 = p.WkvqT + (size_t)(n0 + (tid >> 2)) * KD + (tid & 3) * 8;
    const u16* gb1 = gb0 + (size_t)64 * KD;

    f32x4 acc[4][4];
#pragma unroll
    for (int i = 0; i < 4; i++)
#pragma unroll
        for (int j = 0; j < 4; j++)
            acc[i][j] = (f32x4){0.f, 0.f, 0.f, 0.f};

    const int fm = lane & 15;
    const int fk = (lane >> 4) * 8;

    for (int kt = 0; kt < KD; kt += 32) {
        __syncthreads();
        GLLDS(ga0 + kt, &As[w * 512]);
        GLLDS(ga1 + kt, &As[2048 + w * 512]);
        GLLDS(gb0 + kt, &Bs[w * 512]);
        GLLDS(gb1 + kt, &Bs[2048 + w * 512]);
        __syncthreads();

        bf16x8 af[4], bfr[4];
#pragma unroll
        for (int i = 0; i < 4; i++)
            af[i] = *(const bf16x8*)&As[(wm + i * 16 + fm) * 32 + fk];
#pragma unroll
        for (int j = 0; j < 4; j++)
            bfr[j] = *(const bf16x8*)&Bs[(wn + j * 16 + fm) * 32 + fk];
#pragma unroll
        for (int i = 0; i < 4; i++)
#pragma unroll
            for (int j = 0; j < 4; j++)
                acc[i][j] = __builtin_amdgcn_mfma_f32_16x16x32_bf16(af[i], bfr[j], acc[i][j], 0, 0, 0);
    }

    const int fc = lane & 15;
    const int fr = (lane >> 4) * 4;
    const bool iskv = (n0 < 1024);
#pragma unroll
    for (int i = 0; i < 4; i++)
#pragma unroll
        for (int rr = 0; rr < 4; rr++) {
            int row = m0 + wm + i * 16 + fr + rr;
            if (row < BB * TT) {
                if (iskv) {
#pragma unroll
                    for (int j = 0; j < 4; j++) {
                        int col = n0 + wn + j * 16 + fc;
                        p.kvb[(size_t)row * KVN + col] = f2bf(acc[i][j][rr]);
                    }
                } else {
                    int bb = row / TT;
                    int t  = row - bb * TT;
                    if (t >= CTX - 1) {
                        size_t orow = (size_t)(bb * QL + t - (CTX - 1));
#pragma unroll
                        for (int j = 0; j < 4; j++) {
                            int col = n0 + wn + j * 16 + fc - 1024;
                            p.hqb[orow * HDIM + col] = f2bf(acc[i][j][rr] + p.bq[col]);
                        }
                    }
                }
            }
        }
}

// ---------------------------------------------------------------------------
// G2: bf16 MFMA GEMM 128(M)x64(N), fp32 out. 256 blocks.
// ---------------------------------------------------------------------------
__global__ __launch_bounds__(256) void k_g2(Ptrs p)
{
    __shared__ u16 As[128 * 32];
    __shared__ u16 Bs[64 * 32];

    const int tid  = threadIdx.x;
    const int lane = tid & 63;
    const int w    = tid >> 6;
    const int wm   = (w >> 1) * 64;
    const int wn   = (w & 1) * 32;
    const int m0   = (blockIdx.x >> 3) * 128;
    const int n0   = (blockIdx.x & 7) * 64;

    const u16* ga0 = p.attnb + (size_t)(m0 + (tid >> 2)) * KD + (tid & 3) * 8;
    const u16* ga1 = ga0 + (size_t)64 * KD;
    const u16* gb0 = p.WoT + (size_t)(n0 + (tid >> 2)) * KD + (tid & 3) * 8;

    f32x4 acc[4][2];
#pragma unroll
    for (int i = 0; i < 4; i++)
#pragma unroll
        for (int j = 0; j < 2; j++)
            acc[i][j] = (f32x4){0.f, 0.f, 0.f, 0.f};

    const int fm = lane & 15;
    const int fk = (lane >> 4) * 8;

    for (int kt = 0; kt < KD; kt += 32) {
        __syncthreads();
        GLLDS(ga0 + kt, &As[w * 512]);
        GLLDS(ga1 + kt, &As[2048 + w * 512]);
        GLLDS(gb0 + kt, &Bs[w * 512]);
        __syncthreads();

        bf16x8 af[4], bfr[2];
#pragma unroll
        for (int i = 0; i < 4; i++)
            af[i] = *(const bf16x8*)&As[(wm + i * 16 + fm) * 32 + fk];
#pragma unroll
        for (int j = 0; j < 2; j++)
            bfr[j] = *(const bf16x8*)&Bs[(wn + j * 16 + fm) * 32 + fk];
#pragma unroll
        for (int i = 0; i < 4; i++)
#pragma unroll
            for (int j = 0; j < 2; j++)
                acc[i][j] = __builtin_amdgcn_mfma_f32_16x16x32_bf16(af[i], bfr[j], acc[i][j], 0, 0, 0);
    }

    const int fc = lane & 15;
    const int fr = (lane >> 4) * 4;
#pragma unroll
    for (int i = 0; i < 4; i++)
#pragma unroll
        for (int rr = 0; rr < 4; rr++) {
            int row = m0 + wm + i * 16 + fr + rr;
#pragma unroll
            for (int j = 0; j < 2; j++) {
                int col = n0 + wn + j * 16 + fc;
                p.outp[(size_t)row * DM + col] = acc[i][j][rr];
            }
        }
}

// ---------------------------------------------------------------------------
// MFMA sliding-window relative attention. LDS cut to 37 KB (4 blocks/CU):
// S2 rows (68 f32 = 272 B) and wband rows (136 u16 = 272 B) share one
// [64][272B] region — softmax iteration i reads its s2 row then overwrites
// that exact row with banded bf16 weights + explicit zeros (per-wave row
// ownership; same-thread ordering on aliasing pointers keeps it race-free).
// ---------------------------------------------------------------------------
__global__ __launch_bounds__(256, 4) void k_attn(Ptrs p)
{
    __shared__ __align__(16) char smem[37888];
    float* sprime = (float*)smem;                 // [4][16][80] fp32 (20480 B)
    u16*   vTs    = (u16*)smem;                   // [64][136] (aliases sprime)
    float* s2u    = (float*)(smem + 20480);       // [64][68] fp32 rows, 272 B
    u16*   wband  = (u16*)(smem + 20480);         // [64][136] u16 rows, 272 B

    const int u = blockIdx.x;
    const int q0 = (u & 31) * 64;
    const int h  = (u >> 5) & 7;
    const int b  = u >> 8;
    const int tid  = threadIdx.x;
    const int lane = tid & 63;
    const int w    = tid >> 6;
    const int qb   = q0 + w * 16;

    const int fm = lane & 15;
    const int fk = (lane >> 4) * 8;

    const u16* hqrow = p.hqb + (size_t)(b * QL + qb + fm) * HDIM + h * DH + fk;
    bf16x8 afr0 = *(const bf16x8*)(hqrow);
    bf16x8 afr1 = *(const bf16x8*)(hqrow + 32);

    // QK': S'[16 x 80]
    {
        const u16* kbase = p.kvb + (size_t)(b * TT + qb + fm) * KVN + h * DH + fk;
#pragma unroll
        for (int nt = 0; nt < 5; nt++) {
            bf16x8 b0 = *(const bf16x8*)(kbase + (size_t)nt * 16 * KVN);
            bf16x8 b1 = *(const bf16x8*)(kbase + (size_t)nt * 16 * KVN + 32);
            f32x4 acc = (f32x4){0.f, 0.f, 0.f, 0.f};
            acc = __builtin_amdgcn_mfma_f32_16x16x32_bf16(afr0, b0, acc, 0, 0, 0);
            acc = __builtin_amdgcn_mfma_f32_16x16x32_bf16(afr1, b1, acc, 0, 0, 0);
            const int row = (lane >> 4) * 4;
#pragma unroll
            for (int rr = 0; rr < 4; rr++)
                sprime[w * 1280 + (row + rr) * 80 + nt * 16 + fm] = acc[rr];
        }
    }
    // S2[16 x 64] = hq @ hr^T  -> s2u rows (shared region, pre-band)
    {
        const u16* hrbase = p.hrb + (size_t)fm * HDIM + h * DH + fk;
#pragma unroll
        for (int nc = 0; nc < 4; nc++) {
            bf16x8 b0 = *(const bf16x8*)(hrbase + (size_t)nc * 16 * HDIM);
            bf16x8 b1 = *(const bf16x8*)(hrbase + (size_t)nc * 16 * HDIM + 32);
            f32x4 acc = (f32x4){0.f, 0.f, 0.f, 0.f};
            acc = __builtin_amdgcn_mfma_f32_16x16x32_bf16(afr0, b0, acc, 0, 0, 0);
            acc = __builtin_amdgcn_mfma_f32_16x16x32_bf16(afr1, b1, acc, 0, 0, 0);
            const int row = (lane >> 4) * 4;
#pragma unroll
            for (int rr = 0; rr < 4; rr++)
                s2u[(size_t)(w * 16 + row + rr) * 68 + nc * 16 + fm] = acc[rr];
        }
    }

    // softmax: read s2 row, overwrite same row with banded bf16 weights
#pragma unroll 1
    for (int i = 0; i < 16; i++) {
        const int qloc = w * 16 + i;
        float s = (sprime[w * 1280 + i * 80 + i + lane] +
                   s2u[(size_t)qloc * 68 + lane]) * 0.125f;
        if (q0 == 0) {
            int t = qloc + lane;
            if (t < 63) s += p.maskv[b * 64 + t];
        }
        float mx = s;
#pragma unroll
        for (int off = 32; off; off >>= 1) mx = fmaxf(mx, __shfl_xor(mx, off, 64));
        float e = __expf(s - mx);
        float sum = e;
#pragma unroll
        for (int off = 32; off; off >>= 1) sum += __shfl_xor(sum, off, 64);
        wband[qloc * 136 + qloc + lane] = f2bf(e / sum);
        if (lane < 72) {                       // zero the 72 cols outside band
            int z = (lane < qloc) ? lane : lane + 64;
            wband[qloc * 136 + z] = 0;
        }
    }
    __syncthreads();   // all waves done with sprime/s2u; wband complete

    // stage vT[d][t] (overwrites sprime region)
    {
        const int r0 = tid >> 4;
        const int c4 = (tid & 15) * 4;
        for (int rr = r0; rr < 127; rr += 16) {
            ushort4 vv = *(const ushort4*)&p.kvb[(size_t)(b * TT + q0 + rr) * KVN + HDIM + h * DH + c4];
            vTs[(c4 + 0) * 136 + rr] = vv.x;
            vTs[(c4 + 1) * 136 + rr] = vv.y;
            vTs[(c4 + 2) * 136 + rr] = vv.z;
            vTs[(c4 + 3) * 136 + rr] = vv.w;
        }
        if (tid < 64) vTs[tid * 136 + 127] = 0;
    }
    __syncthreads();

    // PV: O[16 x 64] per wave = W'[16 x 128] @ V[128 x 64]
    f32x4 oacc[4];
#pragma unroll
    for (int j = 0; j < 4; j++) oacc[j] = (f32x4){0.f, 0.f, 0.f, 0.f};
#pragma unroll
    for (int ks = 0; ks < 4; ks++) {
        bf16x8 wa = *(const bf16x8*)&wband[(w * 16 + fm) * 136 + ks * 32 + fk];
#pragma unroll
        for (int j = 0; j < 4; j++) {
            bf16x8 vb = *(const bf16x8*)&vTs[(j * 16 + fm) * 136 + ks * 32 + fk];
            oacc[j] = __builtin_amdgcn_mfma_f32_16x16x32_bf16(wa, vb, oacc[j], 0, 0, 0);
        }
    }
    {
        const int row = (lane >> 4) * 4;
#pragma unroll
        for (int j = 0; j < 4; j++)
#pragma unroll
            for (int rr = 0; rr < 4; rr++)
                p.attnb[(size_t)(b * QL + qb + row + rr) * HDIM + h * DH + j * 16 + fm] =
                    f2bf(oacc[j][rr]);
    }
}

// ---------------------------------------------------------------------------
extern "C" void kernel_launch(void* const* d_in, const int* in_sizes, int n_in,
                              void* d_out, int out_size, void* d_ws, size_t ws_size,
                              hipStream_t stream)
{
    Ptrs p;
    p.x   = (const float*)d_in[0];
    p.r   = (const float*)d_in[1];
    p.Wkv = (const float*)d_in[2];
    p.Wq  = (const float*)d_in[3];
    p.bq  = (const float*)d_in[4];
    p.Wr  = (const float*)d_in[5];
    p.Wo  = (const float*)d_in[6];
    p.outp = (float*)d_out;

    char* w = (char*)d_ws;
    p.xb    = (u16*)w;  w += (size_t)4224 * 512 * 2;
    p.WkvqT = (u16*)w;  w += (size_t)1536 * 512 * 2;
    p.WoT   = (u16*)w;  w += (size_t)512 * 512 * 2;
    p.kvb   = (u16*)w;  w += (size_t)4224 * 1024 * 2;
    p.hqb   = (u16*)w;  w += (size_t)4096 * 512 * 2;
    p.hrb   = (u16*)w;  w += (size_t)64 * 512 * 2;
    p.attnb = (u16*)w;  w += (size_t)4096 * 512 * 2;
    p.maskv = (float*)w;

    hipLaunchKernelGGL(k_prep, dim3(2525),   dim3(256), 0, stream, p);
    hipLaunchKernelGGL(k_g1,   dim3(12, 33), dim3(256), 0, stream, p);
    hipLaunchKernelGGL(k_attn, dim3(512),    dim3(256), 0, stream, p);
    hipLaunchKernelGGL(k_g2,   dim3(256),    dim3(256), 0, stream, p);
}